// Round 1
// baseline (1639.933 us; speedup 1.0000x reference)
//
#include <hip/hip_runtime.h>

#define NN 100000
#define NE 1600000

// ---------------------------------------------------------------------------
// K0: per-node prep.  q[n,:] = x[n,:] @ Wq  (64x64 matvec),
//     g[n,h,i] = sum_c Wk[i, h*16+c] * q[n, h*16+c]   ("folded" Wk so that
//     score[e,h] = sum_i Z[e,i] * g[src,h,i] later — removes the k matvec).
// Also zeroes denom[N,4] and the node-output accumulator region of d_out.
// ---------------------------------------------------------------------------
__global__ __launch_bounds__(256) void node_prep(
    const float* __restrict__ x, const float* __restrict__ Wq,
    const float* __restrict__ Wk, float* __restrict__ g,
    float* __restrict__ denom, float* __restrict__ out_nodes)
{
  // wqT[j*68+i] = Wq[i*64+j]  (transposed, stride 68 => float4-aligned,
  //                            bank (4j+i)%32 — conflict-free in phases)
  // wk [i*68+j] = Wk[i*64+j]  (row-major padded)
  __shared__ float wqT[64 * 68];
  __shared__ float wk[64 * 68];
  __shared__ float xs[4][68];
  __shared__ float qs[4][68];

  const int tid = threadIdx.x;
  for (int idx = tid; idx < 4096; idx += 256) {
    const int i = idx >> 6, j = idx & 63;
    wqT[j * 68 + i] = Wq[idx];
    wk[i * 68 + j]  = Wk[idx];
  }
  __syncthreads();

  const int wave = tid >> 6, lane = tid & 63;
  for (int base = blockIdx.x * 4; base < NN; base += gridDim.x * 4) {
    const int n = base + wave;
    const bool valid = (n < NN);
    if (valid) xs[wave][lane] = x[n * 64 + lane];
    __syncthreads();

    // q_j = sum_i x_i * Wq[i][j]   (lane j owns output j)
    float qv = 0.f;
    #pragma unroll
    for (int i = 0; i < 64; i += 4) {
      const float4 xv = *(const float4*)&xs[wave][i];
      const float4 wv = *(const float4*)&wqT[lane * 68 + i];
      qv += xv.x * wv.x + xv.y * wv.y + xv.z * wv.z + xv.w * wv.w;
    }
    qs[wave][lane] = qv;
    __syncthreads();

    if (valid) {
      // g[n,h,i=lane] = sum_c Wk[lane, h*16+c] * q[h*16+c]
      #pragma unroll
      for (int h = 0; h < 4; h++) {
        float gv = 0.f;
        #pragma unroll
        for (int c = 0; c < 16; c += 4) {
          const float4 q4 = *(const float4*)&qs[wave][h * 16 + c];
          const float4 w4 = *(const float4*)&wk[lane * 68 + h * 16 + c];
          gv += q4.x * w4.x + q4.y * w4.y + q4.z * w4.z + q4.w * w4.w;
        }
        g[n * 256 + h * 64 + lane] = gv;
      }
      out_nodes[n * 64 + lane] = 0.f;   // accumulator must start at 0 (0xAA poison)
      if (lane < 4) denom[n * 4 + lane] = 0.f;
    }
    __syncthreads();  // xs/qs reused next iteration
  }
}

// ---------------------------------------------------------------------------
// K1: one wave per edge (grid-stride).  Per edge:
//   Z = edge_attr[e] * x[nbr]          (lane i owns feature i)
//   score_h = (Z . g[src,h,:]) / 4     (4 simultaneous butterfly reductions)
//   e_h = exp(score_h); atomic denom[src,h] += e_h
//   v = Z @ Wv ; edge_out = Z @ We + be   (Wv/We columns in registers,
//                                          Z broadcast via v_readlane)
//   atomic out[src, h*16+c] += e_h * v
// No segment-max: scores are O(1); exp(max-m) cancels exactly in e/denom.
// ---------------------------------------------------------------------------
__global__ __launch_bounds__(256) void edge_pass(
    const float* __restrict__ x, const int* __restrict__ ei,
    const float* __restrict__ ea, const float* __restrict__ Wv,
    const float* __restrict__ We, const float* __restrict__ be,
    const float* __restrict__ g, float* __restrict__ denom,
    float* __restrict__ out_nodes, float* __restrict__ edge_out)
{
  const int tid  = threadIdx.x;
  const int lane = tid & 63;
  const int wgid = blockIdx.x * 4 + (tid >> 6);
  const int nw   = gridDim.x * 4;

  // lane j holds column j of We and Wv (64+64 VGPRs; ~2 waves/SIMD — the
  // loop is VALU-throughput-bound so occupancy matters less than LDS-free math)
  float wcol[64], vcol[64];
  #pragma unroll
  for (int i = 0; i < 64; i++) {
    wcol[i] = We[i * 64 + lane];
    vcol[i] = Wv[i * 64 + lane];
  }
  const float bias = be[lane];

  for (int e = wgid; e < NE; e += nw) {
    const int s = ei[e];        // src (segment id / q side)
    const int d = ei[NE + e];   // nbr (gathered node)
    const float zv = ea[e * 64 + lane] * x[d * 64 + lane];

    // attention logits via folded-Wk table
    float p0 = zv * g[s * 256 + lane];
    float p1 = zv * g[s * 256 + 64 + lane];
    float p2 = zv * g[s * 256 + 128 + lane];
    float p3 = zv * g[s * 256 + 192 + lane];
    #pragma unroll
    for (int off = 32; off > 0; off >>= 1) {
      p0 += __shfl_xor(p0, off);
      p1 += __shfl_xor(p1, off);
      p2 += __shfl_xor(p2, off);
      p3 += __shfl_xor(p3, off);
    }
    const float e0 = __expf(p0 * 0.25f);
    const float e1 = __expf(p1 * 0.25f);
    const float e2 = __expf(p2 * 0.25f);
    const float e3 = __expf(p3 * 0.25f);

    if (lane < 4) {
      const float ev = (lane == 0) ? e0 : (lane == 1) ? e1 : (lane == 2) ? e2 : e3;
      atomicAdd(&denom[s * 4 + lane], ev);
    }

    // two matvecs sharing the Z broadcast; 4 partial accs to break FMA chains
    float ae0 = bias, ae1 = 0.f, ae2 = 0.f, ae3 = 0.f;
    float av0 = 0.f,  av1 = 0.f, av2 = 0.f, av3 = 0.f;
    #pragma unroll
    for (int i = 0; i < 64; i += 4) {
      const float z0 = __int_as_float(__builtin_amdgcn_readlane(__float_as_int(zv), i + 0));
      const float z1 = __int_as_float(__builtin_amdgcn_readlane(__float_as_int(zv), i + 1));
      const float z2 = __int_as_float(__builtin_amdgcn_readlane(__float_as_int(zv), i + 2));
      const float z3 = __int_as_float(__builtin_amdgcn_readlane(__float_as_int(zv), i + 3));
      ae0 += z0 * wcol[i + 0];  av0 += z0 * vcol[i + 0];
      ae1 += z1 * wcol[i + 1];  av1 += z1 * vcol[i + 1];
      ae2 += z2 * wcol[i + 2];  av2 += z2 * vcol[i + 2];
      ae3 += z3 * wcol[i + 3];  av3 += z3 * vcol[i + 3];
    }
    edge_out[e * 64 + lane] = (ae0 + ae1) + (ae2 + ae3);

    const float vj = (av0 + av1) + (av2 + av3);
    const float eh = (lane < 16) ? e0 : (lane < 32) ? e1 : (lane < 48) ? e2 : e3;
    atomicAdd(&out_nodes[s * 64 + lane], eh * vj);
  }
}

// ---------------------------------------------------------------------------
// K2: out[n, h*16+c] /= (denom[n,h] + 1e-16)  — exactly equal to summing
//     (e/denom)*v per edge, since denom is a common factor per (n,h).
// ---------------------------------------------------------------------------
__global__ __launch_bounds__(256) void normalize_nodes(
    float* __restrict__ out_nodes, const float* __restrict__ denom)
{
  const int i = blockIdx.x * 256 + threadIdx.x;
  if (i < NN * 64) {
    const int n = i >> 6;
    const int h = (i >> 4) & 3;
    out_nodes[i] = out_nodes[i] / (denom[n * 4 + h] + 1e-16f);
  }
}

extern "C" void kernel_launch(void* const* d_in, const int* in_sizes, int n_in,
                              void* d_out, int out_size, void* d_ws, size_t ws_size,
                              hipStream_t stream) {
  const float* x  = (const float*)d_in[0];
  const int*   ei = (const int*)d_in[1];   // [2,E] int32; row0=src, row1=nbr
  const float* ea = (const float*)d_in[2];
  const float* Wq = (const float*)d_in[3];
  const float* Wk = (const float*)d_in[4];
  const float* Wv = (const float*)d_in[5];
  const float* We = (const float*)d_in[6];
  const float* be = (const float*)d_in[7];

  float* out_nodes = (float*)d_out;                 // [N,64]
  float* edge_out  = out_nodes + (size_t)NN * 64;   // [E,64]

  float* g     = (float*)d_ws;                      // [N,4,64]  = 102.4 MB
  float* denom = g + (size_t)NN * 256;              // [N,4]     = 1.6 MB

  node_prep<<<1024, 256, 0, stream>>>(x, Wq, Wk, g, denom, out_nodes);
  edge_pass<<<2048, 256, 0, stream>>>(x, ei, ea, Wv, We, be, g, denom,
                                      out_nodes, edge_out);
  normalize_nodes<<<(NN * 64 + 255) / 256, 256, 0, stream>>>(out_nodes, denom);
}